// Round 13
// baseline (2507.409 us; speedup 1.0000x reference)
//
#include <hip/hip_runtime.h>
#include <stdint.h>

typedef unsigned short u16;
typedef unsigned int u32;
typedef unsigned long long u64;
typedef __attribute__((ext_vector_type(8))) short short8;   // 8 x bf16
typedef __attribute__((ext_vector_type(4))) float f32x4;
typedef __attribute__((ext_vector_type(4))) int int4v;

#define SEQ 256
#define GATE_WGS 64
#define D_WGS 4
#define NWG 69          // 64 gate (barrier-free) + 4 d (m-split) + 1 lazy y
#define A_ELE 49152     // elements per A ring slot (bf16); feat section unused
#define D_ELE 16384

__device__ __forceinline__ u16 f2bf(float f) {
  u32 u = __float_as_uint(f);
  u += 0x7FFFu + ((u >> 16) & 1u);
  return (u16)(u >> 16);
}
__device__ __forceinline__ float bf2f(u16 v) {
  return __uint_as_float(((u32)v) << 16);
}
__device__ __forceinline__ short8 cvt8(const float* __restrict__ p) {
  short8 r;
#pragma unroll
  for (int j = 0; j < 8; ++j) r[j] = (short)f2bf(p[j]);
  return r;
}
__device__ __forceinline__ short8 cvt8v(const float* __restrict__ p) {  // 2x float4
  f32x4 a = *(const f32x4*)p, b = *(const f32x4*)(p + 4);
  short8 r;
#pragma unroll
  for (int j = 0; j < 4; ++j) { r[j] = (short)f2bf(a[j]); r[4 + j] = (short)f2bf(b[j]); }
  return r;
}
__device__ __forceinline__ float fast_tanh(float x) {
  return 1.0f - 2.0f / (1.0f + __expf(2.0f * x));
}
__device__ __forceinline__ float fast_sig(float x) {
  return 1.0f / (1.0f + __expf(-x));
}

union V16 { short8 s; u64 q[2]; };
// device-coherent load/store (bypass L1/L2 -> coherence point), fence-free
__device__ __forceinline__ short8 ldc16(const u16* p) {
  V16 v;
  v.q[0] = __hip_atomic_load((const u64*)p,     __ATOMIC_RELAXED, __HIP_MEMORY_SCOPE_AGENT);
  v.q[1] = __hip_atomic_load((const u64*)p + 1, __ATOMIC_RELAXED, __HIP_MEMORY_SCOPE_AGENT);
  return v.s;
}
__device__ __forceinline__ void stc16(u16* p, const u64* s) {
  __hip_atomic_store((u64*)p,     s[0], __ATOMIC_RELAXED, __HIP_MEMORY_SCOPE_AGENT);
  __hip_atomic_store((u64*)p + 1, s[1], __ATOMIC_RELAXED, __HIP_MEMORY_SCOPE_AGENT);
}
__device__ __forceinline__ void pollge(u32* p, u32 v) {
  while (__hip_atomic_load(p, __ATOMIC_RELAXED, __HIP_MEMORY_SCOPE_AGENT) < v) {}
}
// per-wave store drain: prior coherent stores reach coherence point before flag
#define VMCNT0() asm volatile("s_waitcnt vmcnt(0)" ::: "memory")
// wave-local LDS write->read ordering (no workgroup barrier needed)
#define LGKM0() asm volatile("s_waitcnt lgkmcnt(0)" ::: "memory")

// ---------------------------------------------------------------------------
// prep_misc: zero h slot0 / flags; bcomb = W_fx@b_out + b_fx;
// Wcpack = bf16 frag pack of Wcomb = W_fx @ W_out [256 c][256 dec];
// Whx_pack = bf16 frag pack of W_hx [256 dec rows][512 k].
// ---------------------------------------------------------------------------
__global__ void prep_misc(const float* __restrict__ W_fx, const float* __restrict__ b_fx,
                          const float* __restrict__ W_out, const float* __restrict__ b_out,
                          const float* __restrict__ W_hx,
                          u16* __restrict__ Abuf0, u32* __restrict__ flags,
                          float* __restrict__ bcomb, u16* __restrict__ Wcpack,
                          u16* __restrict__ Whx_pack) {
  int b = blockIdx.x, tid = threadIdx.x;
  if (b == 0) {
    for (int it = 0; it < 16; ++it) {  // zero h-section of slot0: chunks 2048..6143
      int chunk = it * 256 + tid;
      *(int4v*)(Abuf0 + (2048 + chunk) * 8) = (int4v){0, 0, 0, 0};
    }
  } else if (b == 1) {
    for (int k = 0; k < 6; ++k) flags[k * 256 + tid] = 0u;      // 1536 u32
  } else if (b == 2) {
    float s = b_fx[tid];
    for (int k = 0; k < 64; ++k) s += W_fx[tid * 64 + k] * b_out[k];
    bcomb[tid] = s;
  } else if (b < 19) {
    // Wcomb c-tile (b-3): c in [ (b-3)*16, +16 ), all dec
    int ct = b - 3;
    for (int it = 0; it < 16; ++it) {
      int o = it * 256 + tid;
      int cl = o >> 8, dec = o & 255;
      int c = ct * 16 + cl;
      float s = 0.f;
      for (int k = 0; k < 64; ++k) s += W_fx[c * 64 + k] * W_out[k * 256 + dec];
      int dwk = dec >> 5, kd = dec & 31;
      int l = (c & 15) + ((kd >> 3) << 4), j = kd & 7;
      Wcpack[((dwk * 16 + (c >> 4)) * 64 + l) * 8 + j] = f2bf(s);
    }
  } else {
    // Whx pack: 16384 chunks; blocks 19..26, 2048 chunks each.
    int base = (b - 19) * 2048;
#pragma unroll
    for (int it = 0; it < 8; ++it) {
      int cid = base + it * 256 + tid;
      int kb = cid >> 10, rem = cid & 1023, nt16 = rem >> 6, l = rem & 63;
      int row = nt16 * 16 + (l & 15);
      int k = kb * 32 + ((l >> 4) << 3);
      *(short8*)(Whx_pack + cid * 8) = cvt8v(W_hx + row * 512 + k);
    }
  }
}

// ---------------------------------------------------------------------------
// prep_ftf: ftf[t] = tanh(x_t @ W_fx^T + b_fx) as bf16 A-frags, all 256 t.
// ---------------------------------------------------------------------------
__global__ void prep_ftf(const float* __restrict__ x, const float* __restrict__ W_fx,
                         const float* __restrict__ b_fx, u16* __restrict__ ftf) {
  __shared__ __attribute__((aligned(16))) u16 fstage[64 * 264];
  const int t = blockIdx.x, tid = threadIdx.x;
  const int wv = tid >> 6, ln = tid & 63;
  const int c15 = ln & 15, qq = ln >> 4;
  short8 WfR[2][4];
#pragma unroll
  for (int kk = 0; kk < 2; ++kk)
#pragma unroll
    for (int nt = 0; nt < 4; ++nt)
      WfR[kk][nt] = cvt8(W_fx + ((wv * 4 + nt) * 16 + c15) * 64 + kk * 32 + qq * 8);
  float bfx_r[4];
#pragma unroll
  for (int nt = 0; nt < 4; ++nt) bfx_r[nt] = b_fx[(wv * 4 + nt) * 16 + c15];
  short8 xa[2][4];
#pragma unroll
  for (int kb = 0; kb < 2; ++kb)
#pragma unroll
    for (int mt = 0; mt < 4; ++mt)
      xa[kb][mt] = cvt8v(x + (t * 64 + mt * 16 + c15) * 64 + kb * 32 + qq * 8);
  f32x4 tf[4][4];
#pragma unroll
  for (int nt = 0; nt < 4; ++nt)
#pragma unroll
    for (int mt = 0; mt < 4; ++mt) tf[nt][mt] = (f32x4){0.f, 0.f, 0.f, 0.f};
#pragma unroll
  for (int kb = 0; kb < 2; ++kb)
#pragma unroll
    for (int nt = 0; nt < 4; ++nt)
#pragma unroll
      for (int mt = 0; mt < 4; ++mt)
        tf[nt][mt] = __builtin_amdgcn_mfma_f32_16x16x32_bf16(xa[kb][mt], WfR[kb][nt], tf[nt][mt], 0, 0, 0);
#pragma unroll
  for (int nt = 0; nt < 4; ++nt)
#pragma unroll
    for (int mt = 0; mt < 4; ++mt)
#pragma unroll
      for (int r2 = 0; r2 < 4; ++r2) {
        int row = mt * 16 + qq * 4 + r2;
        fstage[row * 264 + (wv * 4 + nt) * 16 + c15] = f2bf(fast_tanh(tf[nt][mt][r2] + bfx_r[nt]));
      }
  __syncthreads();
  u16* ftfb = ftf + t * 16384;
#pragma unroll
  for (int it = 0; it < 8; ++it) {
    int chunk = it * 256 + tid;
    int kb = chunk >> 8, l = chunk & 63;
    int m = ((chunk >> 6) & 3) * 16 + (l & 15);
    int k = kb * 32 + (l >> 4) * 8;
    *(short8*)(ftfb + chunk * 8) = *(const short8*)(fstage + m * 264 + k);
  }
}

// ---------------------------------------------------------------------------
// Persistent recurrent kernel. 69 WGs x 256 threads.
// Gates are BARRIER-FREE / WAVE-AUTONOMOUS: each wave owns batch rows
// mt = wv (16 rows) and computes FULL K=768 for all 32 gate cols (48 MFMAs).
// No cross-wave reduction: i/g and f/o live in lane pairs (n, n+8) -> one
// __shfl_xor(8); both lanes compute identical c,h. h staged via 256B
// wave-local LDS transpose (lgkmcnt, no barrier). Each wave stores its own
// 16-row h chunk, drains, bumps hcnt (64 per step = 16 WGs x 4 waves).
// d WGs: round-12 m-split (local d+feat+blend); y WG off-chain.
// ---------------------------------------------------------------------------
__global__ void __launch_bounds__(256, 1)
rnn_kernel(const float* __restrict__ x, const float* __restrict__ msel,
           const float* __restrict__ W_ih, const float* __restrict__ W_hh,
           const float* __restrict__ b_ih, const float* __restrict__ b_hh,
           const float* __restrict__ b_hx,
           const float* __restrict__ W_out, const float* __restrict__ b_out,
           float* __restrict__ out,
           u16* __restrict__ Abase, u16* __restrict__ dbase,
           u32* __restrict__ flags,
           const float* __restrict__ bcomb, const u16* __restrict__ Wcpack,
           const u16* __restrict__ Whx_pack,
           const u16* __restrict__ ftf, u16* __restrict__ fblend) {
  __shared__ __attribute__((aligned(16))) char smem[109568];
  const int wgid = blockIdx.x;
  const int tid = threadIdx.x;
  const int wv = tid >> 6, ln = tid & 63;
  u32* hcnt  = flags + 1168;   // 4 counters, stride 16; 64 adds per step
  u32* dcnt  = flags + 1232;   // 1 counter (d slices published)
  u32* fbcnt = flags + 1296;   // 2 counters (fblend slots), stride 16

  if (wgid < GATE_WGS) {
    // ===== gate WG, barrier-free: wave wv owns rows [wv*16,+16), K=768 =====
    const int wg = wgid;
    u16* hstage = (u16*)smem;                  // [4 wv][16 rows][8 u] = 1KB
    short8 Breg[24][2];
#pragma unroll
    for (int kb = 0; kb < 24; ++kb)
#pragma unroll
      for (int nt = 0; nt < 2; ++nt) {
        int n = ln & 15, q = ln >> 4;
        int gate = nt * 2 + (n >> 3), unit = n & 7;
        int row = gate * 512 + wg * 8 + unit;
        int k = kb * 32 + q * 8;
        const float* src = (k < 256) ? (W_ih + row * 256 + k) : (W_hh + row * 512 + (k - 256));
        Breg[kb][nt] = cvt8(src);
      }
    float bsum[2];
    {
      int n = ln & 15;
#pragma unroll
      for (int nt = 0; nt < 2; ++nt) {
        int gate = nt * 2 + (n >> 3), unit = n & 7;
        int row = gate * 512 + wg * 8 + unit;
        bsum[nt] = b_ih[row] + b_hh[row];
      }
    }
    f32x4 creg = (f32x4){0.f, 0.f, 0.f, 0.f};
    const int kbW = 8 + (wg >> 2), qW = wg & 3;   // this WG's h region
    const int hi = (ln >> 3) & 1;                 // 1 if lane holds (f,o)
    int r = 0, rn = 1;
    for (int t = 0; t < SEQ; ++t) {
      if (ln < 4) pollge(&hcnt[ln * 16], (u32)(64 * t));
      const u16* A = Abase + r * A_ELE;
      u16* An = Abase + rn * A_ELE;
      f32x4 acc0 = (f32x4){0.f, 0.f, 0.f, 0.f};
      f32x4 acc1 = (f32x4){0.f, 0.f, 0.f, 0.f};
      // --- phase 1: h (kb 8..23 for this wave's row tile) ---
      short8 ah[16];
#pragma unroll
      for (int kh = 0; kh < 16; ++kh)
        ah[kh] = ldc16(A + (((8 + kh) * 4 + wv) * 64 + ln) * 8);
#pragma unroll
      for (int kh = 0; kh < 16; ++kh) {
        acc0 = __builtin_amdgcn_mfma_f32_16x16x32_bf16(ah[kh], Breg[8 + kh][0], acc0, 0, 0, 0);
        acc1 = __builtin_amdgcn_mfma_f32_16x16x32_bf16(ah[kh], Breg[8 + kh][1], acc1, 0, 0, 0);
      }
      // --- phase 2: feat (pre-blended bf16; t=0 -> ftf[0]) ---
      if (ln == 4 && t > 0) pollge(&fbcnt[(t & 1) * 16], 4u * ((u32)(t + 1) >> 1));
      {
        const u16* fsrc = (t == 0) ? ftf : (fblend + (t & 1) * 16384);
        short8 af[8];
#pragma unroll
        for (int kf = 0; kf < 8; ++kf)
          af[kf] = ldc16(fsrc + ((kf * 4 + wv) * 64 + ln) * 8);
#pragma unroll
        for (int kf = 0; kf < 8; ++kf) {
          acc0 = __builtin_amdgcn_mfma_f32_16x16x32_bf16(af[kf], Breg[kf][0], acc0, 0, 0, 0);
          acc1 = __builtin_amdgcn_mfma_f32_16x16x32_bf16(af[kf], Breg[kf][1], acc1, 0, 0, 0);
        }
      }
      // --- LSTM, wave-local: lane n holds (i,g), lane n+8 holds (f,o) ---
      f32x4 h4;
#pragma unroll
      for (int reg = 0; reg < 4; ++reg) {
        float g0 = acc0[reg] + bsum[0];
        float g1 = acc1[reg] + bsum[1];
        float p0 = __shfl_xor(g0, 8, 64);
        float p1 = __shfl_xor(g1, 8, 64);
        float iv = hi ? p0 : g0;
        float fv = hi ? g0 : p0;
        float gv = hi ? p1 : g1;
        float ov = hi ? g1 : p1;
        float cn = fast_sig(fv) * creg[reg] + fast_sig(iv) * fast_tanh(gv);
        creg[reg] = cn;
        h4[reg] = fast_sig(ov) * fast_tanh(cn);
      }
      // stage h to wave-local LDS (transpose (4rows x 1unit) -> 16B row chunks)
      if ((ln & 15) < 8) {
#pragma unroll
        for (int reg = 0; reg < 4; ++reg)
          hstage[wv * 128 + ((ln >> 4) * 4 + reg) * 8 + (ln & 7)] = f2bf(h4[reg]);
      }
      LGKM0();
      if (ln < 16)
        stc16(An + (((kbW * 4 + wv) * 64 + qW * 16 + ln) * 8),
              (const u64*)(hstage + wv * 128 + ln * 8));
      VMCNT0();
      if (ln == 0)
        (void)__hip_atomic_fetch_add(&hcnt[(wg & 3) * 16], 1u,
                                     __ATOMIC_RELAXED, __HIP_MEMORY_SCOPE_AGENT);
      r = rn; rn = (rn == 2) ? 0 : rn + 1;
    }
  } else if (wgid < GATE_WGS + D_WGS) {
    // ===== d WG (m-split): 16 batch rows, ALL dec; then feat+blend local =====
    const int dw = wgid - GATE_WGS;            // owns batch rows [dw*16, +16)
    u16* dstage = (u16*)smem;                  // [16][264] bf16 = 8448 B
    float* fstg = (float*)(smem + 8448);       // [16][264] f32 = 16896 B
    float bhx_r[4];
#pragma unroll
    for (int ntl = 0; ntl < 4; ++ntl) bhx_r[ntl] = b_hx[(wv * 4 + ntl) * 16 + (ln & 15)];
    int r = 0, rn = 1;
    for (int t = 0; t < SEQ; ++t) {
      if (tid < 4) pollge(&hcnt[tid * 16], (u32)(64 * t));
      __syncthreads();
      const u16* A = Abase + r * A_ELE;
      u16* dbufR = dbase + (t & 3) * D_ELE;
      // A-frags: h rows [dw*16,+16): chunks ((8+kbh)*4 + dw)*64 + ln
      short8 ah[16];
#pragma unroll
      for (int kbh = 0; kbh < 16; ++kbh)
        ah[kbh] = ldc16(A + (((8 + kbh) * 4 + dw) * 64 + ln) * 8);
      // d GEMM: wave wv owns dec cols [wv*64,+64), FULL K=512 (no reduce)
      f32x4 acc[4];
#pragma unroll
      for (int ntl = 0; ntl < 4; ++ntl) acc[ntl] = (f32x4){0.f, 0.f, 0.f, 0.f};
#pragma unroll
      for (int kbh = 0; kbh < 16; ++kbh) {
#pragma unroll
        for (int ntl = 0; ntl < 4; ++ntl) {
          short8 bw = *(const short8*)(Whx_pack + ((kbh * 16 + wv * 4 + ntl) * 64 + ln) * 8);
          acc[ntl] = __builtin_amdgcn_mfma_f32_16x16x32_bf16(ah[kbh], bw, acc[ntl], 0, 0, 0);
        }
      }
      // finalize: d[m = dw*16 + (ln>>4)*4+reg][dec = (wv*4+ntl)*16 + (ln&15)]
#pragma unroll
      for (int ntl = 0; ntl < 4; ++ntl)
#pragma unroll
        for (int reg = 0; reg < 4; ++reg)
          dstage[((ln >> 4) * 4 + reg) * 264 + (wv * 4 + ntl) * 16 + (ln & 15)]
              = f2bf(fast_tanh(acc[ntl][reg] + bhx_r[ntl]));
      __syncthreads();
      // d publish (512 frag chunks, 2/thread) — drain deferred to end
#pragma unroll
      for (int s = 0; s < 2; ++s) {
        int cl = s * 256 + tid;
        int kd = cl >> 6, l = cl & 63;
        V16 v; v.s = *(const short8*)(dstage + (l & 15) * 264 + kd * 32 + (l >> 4) * 8);
        stc16(dbufR + ((kd * 4 + dw) * 64 + l) * 8, v.q);
      }
      if (t < SEQ - 1) {
        // feat GEMM: A = local dstage rows, B = Wcomb; wave owns c [wv*64,+64)
        f32x4 acc2[4];
#pragma unroll
        for (int ntf = 0; ntf < 4; ++ntf) acc2[ntf] = (f32x4){0.f, 0.f, 0.f, 0.f};
#pragma unroll
        for (int kd = 0; kd < 8; ++kd) {
          short8 ad = *(const short8*)(dstage + (ln & 15) * 264 + kd * 32 + (ln >> 4) * 8);
#pragma unroll
          for (int ntf = 0; ntf < 4; ++ntf) {
            short8 bw = *(const short8*)(Wcpack + ((kd * 16 + wv * 4 + ntf) * 64 + ln) * 8);
            acc2[ntf] = __builtin_amdgcn_mfma_f32_16x16x32_bf16(ad, bw, acc2[ntf], 0, 0, 0);
          }
        }
        // stage feat rows to LDS: fstg[m&15][c]
#pragma unroll
        for (int ntf = 0; ntf < 4; ++ntf)
#pragma unroll
          for (int reg = 0; reg < 4; ++reg)
            fstg[((ln >> 4) * 4 + reg) * 264 + (wv * 4 + ntf) * 16 + (ln & 15)] = acc2[ntf][reg];
        __syncthreads();
        // blend + store fblend (512 frag chunks, 2/thread)
        float mixg = msel[t + 1];
        const u16* ftfb = ftf + (t + 1) * 16384;
        u16* fbl = fblend + ((t + 1) & 1) * 16384;
#pragma unroll
        for (int s = 0; s < 2; ++s) {
          int cl = s * 256 + tid;
          int kb = cl >> 6, l = cl & 63;
          int c0 = kb * 32 + (l >> 4) * 8;
          const float* fr = fstg + (l & 15) * 264 + c0;
          short8 tfv = *(const short8*)(ftfb + ((kb * 4 + dw) * 64 + l) * 8);
          short8 rr;
#pragma unroll
          for (int j = 0; j < 8; ++j) {
            float av = fr[j] + bcomb[c0 + j];
            rr[j] = (short)f2bf(mixg * fast_tanh(av) + (1.f - mixg) * bf2f((u16)tfv[j]));
          }
          V16 v; v.s = rr;
          stc16(fbl + ((kb * 4 + dw) * 64 + l) * 8, v.q);
        }
        VMCNT0();
        __syncthreads();
        if (tid == 0) {
          (void)__hip_atomic_fetch_add(dcnt, 1u, __ATOMIC_RELAXED, __HIP_MEMORY_SCOPE_AGENT);
          (void)__hip_atomic_fetch_add(&fbcnt[((t + 1) & 1) * 16], 1u,
                                       __ATOMIC_RELAXED, __HIP_MEMORY_SCOPE_AGENT);
        }
      } else {
        VMCNT0();
        __syncthreads();
        if (tid == 0)
          (void)__hip_atomic_fetch_add(dcnt, 1u, __ATOMIC_RELAXED, __HIP_MEMORY_SCOPE_AGENT);
      }
      r = rn; rn = (rn == 2) ? 0 : rn + 1;
    }
  } else {
    // ===== lazy y WG (off the recurrence): y = d @ W_out^T + b_out =====
    float* red = (float*)smem;                 // [4 wv][16 tile][64][4] = 64KB
    const int c15 = ln & 15, qq = ln >> 4;
    short8 WoR[2][4];
#pragma unroll
    for (int kk = 0; kk < 2; ++kk) {
      int koffo = (wv * 2 + kk) * 32 + qq * 8;
#pragma unroll
      for (int nt = 0; nt < 4; ++nt)
        WoR[kk][nt] = cvt8(W_out + (nt * 16 + c15) * 256 + koffo);
    }
    float bout_r = b_out[wv * 16 + c15];
    for (int t = 0; t < SEQ; ++t) {
      if (tid == 0) pollge(dcnt, 4u * (u32)(t + 1));
      __syncthreads();
      const u16* dbufR = dbase + (t & 3) * D_ELE;
      short8 da[2][4];
#pragma unroll
      for (int kk = 0; kk < 2; ++kk)
#pragma unroll
        for (int mt = 0; mt < 4; ++mt)
          da[kk][mt] = ldc16(dbufR + (((wv * 2 + kk) * 4 + mt) * 64 + ln) * 8);
      f32x4 acc[4][4];
#pragma unroll
      for (int nt = 0; nt < 4; nt++)
#pragma unroll
        for (int mt = 0; mt < 4; mt++) acc[nt][mt] = (f32x4){0.f, 0.f, 0.f, 0.f};
#pragma unroll
      for (int kk = 0; kk < 2; ++kk)
#pragma unroll
        for (int nt = 0; nt < 4; nt++)
#pragma unroll
          for (int mt = 0; mt < 4; mt++)
            acc[nt][mt] = __builtin_amdgcn_mfma_f32_16x16x32_bf16(da[kk][mt], WoR[kk][nt], acc[nt][mt], 0, 0, 0);
#pragma unroll
      for (int nt = 0; nt < 4; nt++)
#pragma unroll
        for (int mt = 0; mt < 4; mt++)
          *(f32x4*)(red + ((wv * 16 + nt * 4 + mt) * 64 + ln) * 4) = acc[nt][mt];
      __syncthreads();
#pragma unroll
      for (int mt = 0; mt < 4; ++mt) {
        f32x4 s = (f32x4){0.f, 0.f, 0.f, 0.f};
#pragma unroll
        for (int w2 = 0; w2 < 4; ++w2)
          s += *(const f32x4*)(red + ((w2 * 16 + wv * 4 + mt) * 64 + ln) * 4);
#pragma unroll
        for (int r2 = 0; r2 < 4; ++r2) {
          int row = mt * 16 + qq * 4 + r2;
          out[t * 4096 + row * 64 + wv * 16 + c15] = s[r2] + bout_r;
        }
      }
      __syncthreads();
    }
  }
}

extern "C" void kernel_launch(void* const* d_in, const int* in_sizes, int n_in,
                              void* d_out, int out_size, void* d_ws, size_t ws_size,
                              hipStream_t stream) {
  const float* x     = (const float*)d_in[0];
  const float* msel  = (const float*)d_in[1];
  const float* W_fx  = (const float*)d_in[2];
  const float* b_fx  = (const float*)d_in[3];
  const float* W_ih  = (const float*)d_in[4];
  const float* W_hh  = (const float*)d_in[5];
  const float* b_ih  = (const float*)d_in[6];
  const float* b_hh  = (const float*)d_in[7];
  const float* W_hx  = (const float*)d_in[8];
  const float* b_hx  = (const float*)d_in[9];
  const float* W_out = (const float*)d_in[10];
  const float* b_out = (const float*)d_in[11];

  uint8_t* ws = (uint8_t*)d_ws;
  u16*   Abase    = (u16*)ws;                 // ring of 3 x 98304 B
  u16*   dbase    = (u16*)(ws + 294912);      // ring of 4 x 32768 B
  u32*   flags    = (u32*)(ws + 425984);      // 6144 B (u32[1536])
  float* bcomb    = (float*)(ws + 432128);    // 1024 B
  u16*   Wcpack   = (u16*)(ws + 433152);      // 131072 B
  u16*   fblend   = (u16*)(ws + 564224);      // 2 x 32768 B
  u16*   Whx_pack = (u16*)(ws + 629760);      // 262144 B
  u16*   ftf      = (u16*)(ws + 891904);      // 256 x 32768 B = 8 MB

  prep_misc<<<27, 256, 0, stream>>>(W_fx, b_fx, W_out, b_out, W_hx,
                                    Abase, flags, bcomb, Wcpack, Whx_pack);
  prep_ftf<<<256, 256, 0, stream>>>(x, W_fx, b_fx, ftf);
  rnn_kernel<<<NWG, 256, 0, stream>>>(x, msel, W_ih, W_hh, b_ih, b_hh,
                                      b_hx, W_out, b_out,
                                      (float*)d_out, Abase, dbase, flags,
                                      bcomb, Wcpack, Whx_pack, ftf, fblend);
}

// Round 14
// 2135.306 us; speedup vs baseline: 1.1743x; 1.1743x over previous
//
#include <hip/hip_runtime.h>
#include <stdint.h>

typedef unsigned short u16;
typedef unsigned int u32;
typedef unsigned long long u64;
typedef __attribute__((ext_vector_type(8))) short short8;   // 8 x bf16
typedef __attribute__((ext_vector_type(4))) float f32x4;
typedef __attribute__((ext_vector_type(4))) int int4v;

#define SEQ 256
#define GATE_WGS 64
#define D_WGS 8
#define NWG 73          // 64 gate + 8 d (feat-partial producers) + 1 lazy y
#define A_ELE 49152     // elements per A ring slot (bf16); feat section unused
#define D_ELE 16384
#define FACC_ELE 16384  // f32 per featacc slot (64 m x 256 c)

__device__ __forceinline__ u16 f2bf(float f) {
  u32 u = __float_as_uint(f);
  u += 0x7FFFu + ((u >> 16) & 1u);
  return (u16)(u >> 16);
}
__device__ __forceinline__ float bf2f(u16 v) {
  return __uint_as_float(((u32)v) << 16);
}
__device__ __forceinline__ short8 cvt8(const float* __restrict__ p) {
  short8 r;
#pragma unroll
  for (int j = 0; j < 8; ++j) r[j] = (short)f2bf(p[j]);
  return r;
}
__device__ __forceinline__ short8 cvt8v(const float* __restrict__ p) {  // 2x float4
  f32x4 a = *(const f32x4*)p, b = *(const f32x4*)(p + 4);
  short8 r;
#pragma unroll
  for (int j = 0; j < 4; ++j) { r[j] = (short)f2bf(a[j]); r[4 + j] = (short)f2bf(b[j]); }
  return r;
}
__device__ __forceinline__ float fast_tanh(float x) {
  return 1.0f - 2.0f / (1.0f + __expf(2.0f * x));
}
__device__ __forceinline__ float fast_sig(float x) {
  return 1.0f / (1.0f + __expf(-x));
}

union V16 { short8 s; u64 q[2]; };
// device-coherent load/store (bypass L1/L2 -> coherence point), fence-free
__device__ __forceinline__ short8 ldc16(const u16* p) {
  V16 v;
  v.q[0] = __hip_atomic_load((const u64*)p,     __ATOMIC_RELAXED, __HIP_MEMORY_SCOPE_AGENT);
  v.q[1] = __hip_atomic_load((const u64*)p + 1, __ATOMIC_RELAXED, __HIP_MEMORY_SCOPE_AGENT);
  return v.s;
}
__device__ __forceinline__ f32x4 ldc16f(const float* p) {
  union { f32x4 f; u64 q[2]; } v;
  v.q[0] = __hip_atomic_load((const u64*)p,     __ATOMIC_RELAXED, __HIP_MEMORY_SCOPE_AGENT);
  v.q[1] = __hip_atomic_load((const u64*)p + 1, __ATOMIC_RELAXED, __HIP_MEMORY_SCOPE_AGENT);
  return v.f;
}
__device__ __forceinline__ void stc16(u16* p, const u64* s) {
  __hip_atomic_store((u64*)p,     s[0], __ATOMIC_RELAXED, __HIP_MEMORY_SCOPE_AGENT);
  __hip_atomic_store((u64*)p + 1, s[1], __ATOMIC_RELAXED, __HIP_MEMORY_SCOPE_AGENT);
}
__device__ __forceinline__ void atadd(float* p, float v) {
  (void)__hip_atomic_fetch_add(p, v, __ATOMIC_RELAXED, __HIP_MEMORY_SCOPE_AGENT);
}
__device__ __forceinline__ void pollge(u32* p, u32 v) {
  while (__hip_atomic_load(p, __ATOMIC_RELAXED, __HIP_MEMORY_SCOPE_AGENT) < v) {}
}
__device__ __forceinline__ void setflag(u32* p, u32 v) {
  __hip_atomic_store(p, v, __ATOMIC_RELAXED, __HIP_MEMORY_SCOPE_AGENT);
}
// per-wave store drain: prior coherent stores reach coherence point before flag
#define VMCNT0() asm volatile("s_waitcnt vmcnt(0)" ::: "memory")

// ---------------------------------------------------------------------------
// prep_misc: zero h slot0 / flags / featacc; bcomb = W_fx@b_out + b_fx;
// Wcpack = bf16 MFMA-B-frag pack of Wcomb = W_fx @ W_out  [256 c][256 dec].
// ---------------------------------------------------------------------------
__global__ void prep_misc(const float* __restrict__ W_fx, const float* __restrict__ b_fx,
                          const float* __restrict__ W_out, const float* __restrict__ b_out,
                          u16* __restrict__ Abuf0, u32* __restrict__ flags,
                          float* __restrict__ featacc, float* __restrict__ bcomb,
                          u16* __restrict__ Wcpack) {
  int b = blockIdx.x, tid = threadIdx.x;
  if (b == 0) {
    for (int it = 0; it < 16; ++it) {  // zero h-section of slot0: chunks 2048..6143
      int chunk = it * 256 + tid;
      *(int4v*)(Abuf0 + (2048 + chunk) * 8) = (int4v){0, 0, 0, 0};
    }
  } else if (b == 1) {
    for (int k = 0; k < 6; ++k) flags[k * 256 + tid] = 0u;      // 1536 u32
  } else if (b < 6) {
    float* base = featacc + (b - 2) * 16384;                    // quarter = 16K f32
    for (int it = 0; it < 16; ++it)
      *(f32x4*)(base + (it * 256 + tid) * 4) = (f32x4){0.f, 0.f, 0.f, 0.f};
  } else if (b == 6) {
    float s = b_fx[tid];
    for (int k = 0; k < 64; ++k) s += W_fx[tid * 64 + k] * b_out[k];
    bcomb[tid] = s;
  } else {
    // Wcomb c-tile (b-7): c in [ (b-7)*16, +16 ), all dec
    int ct = b - 7;
    for (int it = 0; it < 16; ++it) {
      int o = it * 256 + tid;
      int cl = o >> 8, dec = o & 255;
      int c = ct * 16 + cl;
      float s = 0.f;
      for (int k = 0; k < 64; ++k) s += W_fx[c * 64 + k] * W_out[k * 256 + dec];
      int dwk = dec >> 5, kd = dec & 31;
      int l = (c & 15) + ((kd >> 3) << 4), j = kd & 7;
      Wcpack[((dwk * 16 + (c >> 4)) * 64 + l) * 8 + j] = f2bf(s);
    }
  }
}

// ---------------------------------------------------------------------------
// prep_ftf: ftf[t] = tanh(x_t @ W_fx^T + b_fx) as bf16 A-frags, all 256 t.
// ---------------------------------------------------------------------------
__global__ void prep_ftf(const float* __restrict__ x, const float* __restrict__ W_fx,
                         const float* __restrict__ b_fx, u16* __restrict__ ftf) {
  __shared__ __attribute__((aligned(16))) u16 fstage[64 * 264];
  const int t = blockIdx.x, tid = threadIdx.x;
  const int wv = tid >> 6, ln = tid & 63;
  const int c15 = ln & 15, qq = ln >> 4;
  short8 WfR[2][4];
#pragma unroll
  for (int kk = 0; kk < 2; ++kk)
#pragma unroll
    for (int nt = 0; nt < 4; ++nt)
      WfR[kk][nt] = cvt8(W_fx + ((wv * 4 + nt) * 16 + c15) * 64 + kk * 32 + qq * 8);
  float bfx_r[4];
#pragma unroll
  for (int nt = 0; nt < 4; ++nt) bfx_r[nt] = b_fx[(wv * 4 + nt) * 16 + c15];
  short8 xa[2][4];
#pragma unroll
  for (int kb = 0; kb < 2; ++kb)
#pragma unroll
    for (int mt = 0; mt < 4; ++mt)
      xa[kb][mt] = cvt8v(x + (t * 64 + mt * 16 + c15) * 64 + kb * 32 + qq * 8);
  f32x4 tf[4][4];
#pragma unroll
  for (int nt = 0; nt < 4; ++nt)
#pragma unroll
    for (int mt = 0; mt < 4; ++mt) tf[nt][mt] = (f32x4){0.f, 0.f, 0.f, 0.f};
#pragma unroll
  for (int kb = 0; kb < 2; ++kb)
#pragma unroll
    for (int nt = 0; nt < 4; ++nt)
#pragma unroll
      for (int mt = 0; mt < 4; ++mt)
        tf[nt][mt] = __builtin_amdgcn_mfma_f32_16x16x32_bf16(xa[kb][mt], WfR[kb][nt], tf[nt][mt], 0, 0, 0);
#pragma unroll
  for (int nt = 0; nt < 4; ++nt)
#pragma unroll
    for (int mt = 0; mt < 4; ++mt)
#pragma unroll
      for (int r2 = 0; r2 < 4; ++r2) {
        int row = mt * 16 + qq * 4 + r2;
        fstage[row * 264 + (wv * 4 + nt) * 16 + c15] = f2bf(fast_tanh(tf[nt][mt][r2] + bfx_r[nt]));
      }
  __syncthreads();
  u16* ftfb = ftf + t * 16384;
#pragma unroll
  for (int it = 0; it < 8; ++it) {
    int chunk = it * 256 + tid;
    int kb = chunk >> 8, l = chunk & 63;
    int m = ((chunk >> 6) & 3) * 16 + (l & 15);
    int k = kb * 32 + (l >> 4) * 8;
    *(short8*)(ftfb + chunk * 8) = *(const short8*)(fstage + m * 264 + k);
  }
}

// ---------------------------------------------------------------------------
// Persistent recurrent kernel. 73 WGs x 256 threads. Round-6 structure with
// FEAT-FIRST gate ordering: feat_t depends on h_{t-1} (2 steps of slack), so
// it is READY before h_t. Gates poll fcnt first and build feat fragments in
// registers while h_t is still in flight; only {h gather, MFMA, LSTM, store}
// remain on the h-critical path.
//   hcnt[j] += 1 (j=wg&3) after gate wg stored h_{t+1} (+ featacc zeroes)
//   d WGs: h_t -> d_t; atomic-add Wcomb partials into featacc[t&3];
//     drain; dflag=t+1; fcnt[t&3]++.  y WG off-chain via dflag.
// featacc 4-slot ring: add@t, read@t+1, zero@t+2 (by gates, race-free), idle.
// ---------------------------------------------------------------------------
__global__ void __launch_bounds__(256, 1)
rnn_kernel(const float* __restrict__ x, const float* __restrict__ msel,
           const float* __restrict__ W_ih, const float* __restrict__ W_hh,
           const float* __restrict__ b_ih, const float* __restrict__ b_hh,
           const float* __restrict__ W_hx, const float* __restrict__ b_hx,
           const float* __restrict__ W_out, const float* __restrict__ b_out,
           float* __restrict__ out,
           u16* __restrict__ Abase, u16* __restrict__ dbase,
           u32* __restrict__ flags, float* __restrict__ featacc,
           const float* __restrict__ bcomb, const u16* __restrict__ Wcpack,
           const u16* __restrict__ ftf) {
  __shared__ __attribute__((aligned(16))) char smem[109568];
  const int wgid = blockIdx.x;
  const int tid = threadIdx.x;
  const int wv = tid >> 6, ln = tid & 63;
  u32* dflag = flags + 1024;   // stride 16 u32
  u32* hcnt  = flags + 1168;   // 4 counters, stride 16
  u32* fcnt  = flags + 1232;   // 4 counters (featacc slots), stride 16

  if (wgid < GATE_WGS) {
    // ===== gate WG: kb remap kb = wv + kk*4 (kk 0,1 = feat; 2..5 = h) =====
    const int wg = wgid;
    float* red = (float*)smem;                 // [4 wv][8 tile][64][4] = 32KB
    u16* hstage = (u16*)(smem + 32768);        // 1KB
    short8 Breg[6][2];
#pragma unroll
    for (int kk = 0; kk < 6; ++kk) {
      int kb = wv + kk * 4;
#pragma unroll
      for (int nt = 0; nt < 2; ++nt) {
        int n = ln & 15, q = ln >> 4;
        int gate = nt * 2 + (n >> 3), unit = n & 7;
        int row = gate * 512 + wg * 8 + unit;
        int k = kb * 32 + q * 8;
        const float* src = (k < 256) ? (W_ih + row * 256 + k) : (W_hh + row * 512 + (k - 256));
        Breg[kk][nt] = cvt8(src);
      }
    }
    float bcomb_r[2][8];
#pragma unroll
    for (int kk = 0; kk < 2; ++kk)
#pragma unroll
      for (int j = 0; j < 8; ++j)
        bcomb_r[kk][j] = bcomb[(wv + kk * 4) * 32 + (ln >> 4) * 8 + j];
    float bsum_r[2][4];
#pragma unroll
    for (int it = 0; it < 2; ++it) {
      int u = (it * 256 + tid) & 7;
#pragma unroll
      for (int g = 0; g < 4; ++g) {
        int row = g * 512 + wg * 8 + u;
        bsum_r[it][g] = b_ih[row] + b_hh[row];
      }
    }
    float creg[2] = {0.f, 0.f};
    const int kbW = 8 + (wg >> 2), qW = wg & 3;   // this WG's h region
    int r = 0, rn = 1;
    for (int t = 0; t < SEQ; ++t) {
      // prefetch ftf[t] (plain cached loads, flag-independent) + msel[t]
      const u16* ftfb = ftf + t * 16384;
      short8 tf8[2][4];
#pragma unroll
      for (int kk = 0; kk < 2; ++kk) {
        int kb = wv + kk * 4;
#pragma unroll
        for (int mt = 0; mt < 4; ++mt)
          tf8[kk][mt] = *(const short8*)(ftfb + ((kb * 4 + mt) * 64 + ln) * 8);
      }
      float mixg = (t > 0) ? msel[t] : 0.f;
      // --- FEAT-FIRST: feat_t is ready early (depends on h_{t-1}) ---
      if (tid == 64 && t > 0)
        pollge(&fcnt[((t - 1) & 3) * 16], 8u * (((u32)(t - 1) >> 2) + 1u));
      __syncthreads();
      short8 a[6][4];
      if (t == 0) {
#pragma unroll
        for (int kk = 0; kk < 2; ++kk)
#pragma unroll
          for (int mt = 0; mt < 4; ++mt)
            a[kk][mt] = tf8[kk][mt];
      } else {
        const float* fs = featacc + ((t - 1) & 3) * FACC_ELE;
#pragma unroll
        for (int kk = 0; kk < 2; ++kk) {
          int kb = wv + kk * 4;
#pragma unroll
          for (int mt = 0; mt < 4; ++mt) {
            int ch = (kb * 4 + mt) * 64 + ln;
            f32x4 lo = ldc16f(fs + ch * 8);
            f32x4 hi = ldc16f(fs + ch * 8 + 4);
            short8 tfv = tf8[kk][mt];
            short8 rr;
#pragma unroll
            for (int j = 0; j < 8; ++j) {
              float av = ((j < 4) ? lo[j] : hi[j - 4]) + bcomb_r[kk][j];
              float fv = mixg * fast_tanh(av) + (1.f - mixg) * bf2f((u16)tfv[j]);
              rr[j] = (short)f2bf(fv);
            }
            a[kk][mt] = rr;
          }
        }
      }
      // --- NOW wait for h_t; only h work remains on the critical path ---
      if (tid < 4) pollge(&hcnt[tid * 16], (u32)(16 * t));
      __syncthreads();
      const u16* A = Abase + r * A_ELE;
      u16* An = Abase + rn * A_ELE;
#pragma unroll
      for (int kk = 2; kk < 6; ++kk) {
        int kb = wv + kk * 4;
#pragma unroll
        for (int mt = 0; mt < 4; ++mt)
          a[kk][mt] = ldc16(A + ((kb * 4 + mt) * 64 + ln) * 8);
      }
      f32x4 acc[2][4];
#pragma unroll
      for (int nt = 0; nt < 2; nt++)
#pragma unroll
        for (int mt = 0; mt < 4; mt++) acc[nt][mt] = (f32x4){0.f, 0.f, 0.f, 0.f};
#pragma unroll
      for (int kk = 0; kk < 6; ++kk)
#pragma unroll
        for (int nt = 0; nt < 2; nt++)
#pragma unroll
          for (int mt = 0; mt < 4; mt++)
            acc[nt][mt] = __builtin_amdgcn_mfma_f32_16x16x32_bf16(a[kk][mt], Breg[kk][nt], acc[nt][mt], 0, 0, 0);
      // one-shot 4-wave reduction staging
#pragma unroll
      for (int nt = 0; nt < 2; nt++)
#pragma unroll
        for (int mt = 0; mt < 4; mt++)
          *(f32x4*)(red + ((wv * 8 + nt * 4 + mt) * 64 + ln) * 4) = acc[nt][mt];
      __syncthreads();
      // LSTM cell: 512 (m,u) items, 2/thread; sum 4 wave-partials inline
#pragma unroll
      for (int it = 0; it < 2; ++it) {
        int item = it * 256 + tid;
        int m = item >> 3, u = item & 7;
        int mt = m >> 4, lq = ((m & 15) >> 2) * 16, reg = m & 3;
        float g4[4];
#pragma unroll
        for (int g = 0; g < 4; ++g) {
          float s = bsum_r[it][g];
          int base = ((g >> 1) * 4 + mt) * 64 + lq + (g & 1) * 8 + u;
#pragma unroll
          for (int w = 0; w < 4; ++w) s += red[(w * 8 * 64 + base) * 4 + reg];
          g4[g] = s;
        }
        float ii = fast_sig(g4[0]), ff = fast_sig(g4[1]);
        float gg = fast_tanh(g4[2]), oo = fast_sig(g4[3]);
        float cn = ff * creg[it] + ii * gg;
        creg[it] = cn;
        float h = oo * fast_tanh(cn);
        hstage[(mt * 16 + (m & 15)) * 8 + u] = f2bf(h);
      }
      __syncthreads();
      if (tid < 64) {
        // zero this WG's 1KB share of featacc slot (t+2)&3 (quiescent slot);
        // drained by the same VMCNT0 as the h store -> covered by hcnt.
        u64 zq[2] = {0ull, 0ull};
        u16* fz = (u16*)featacc + ((t + 2) & 3) * 32768 + wg * 512 + tid * 8;
        stc16(fz, zq);
        int mt2 = tid >> 4, m15 = tid & 15;
        u16* dst = An + (((kbW * 4 + mt2) * 64 + qW * 16 + m15) * 8);
        stc16(dst, (const u64*)(hstage + tid * 8));
        VMCNT0();
        if (tid == 0)
          (void)__hip_atomic_fetch_add(&hcnt[(wg & 3) * 16], 1u,
                                       __ATOMIC_RELAXED, __HIP_MEMORY_SCOPE_AGENT);
      }
      r = rn; rn = (rn == 2) ? 0 : rn + 1;
    }
  } else if (wgid < GATE_WGS + D_WGS) {
    // ===== d WG: d slice + Wcomb feat-partial atomic-add =====
    const int dw = wgid - GATE_WGS;
    float* red = (float*)smem;                 // 32KB
    u16* dstage = (u16*)(smem + 32768);        // 4KB
    short8 Breg[4][2];
#pragma unroll
    for (int kk = 0; kk < 4; ++kk) {
      int kbh = wv * 4 + kk;
#pragma unroll
      for (int nt = 0; nt < 2; ++nt) {
        int n = ln & 15, q = ln >> 4;
        int row = dw * 32 + nt * 16 + n;
        int k = kbh * 32 + q * 8;
        Breg[kk][nt] = cvt8(W_hx + row * 512 + k);
      }
    }
    short8 WcB[4];   // Wcomb B-frags: this wave's 4 c-tiles, this WG's 32 dec k's
#pragma unroll
    for (int nt = 0; nt < 4; ++nt)
      WcB[nt] = *(const short8*)(Wcpack + ((dw * 16 + wv * 4 + nt) * 64 + ln) * 8);
    float bias_r[8];
#pragma unroll
    for (int it = 0; it < 8; ++it) bias_r[it] = b_hx[dw * 32 + ((it * 256 + tid) & 31)];
    int r = 0, rn = 1;
    for (int t = 0; t < SEQ; ++t) {
      if (tid < 4) pollge(&hcnt[tid * 16], (u32)(16 * t));
      __syncthreads();
      const u16* A = Abase + r * A_ELE;
      u16* dbufR = dbase + (t & 1) * D_ELE;
      short8 a[4][4];
#pragma unroll
      for (int kk = 0; kk < 4; ++kk)
#pragma unroll
        for (int mt = 0; mt < 4; ++mt)
          a[kk][mt] = ldc16(A + (((8 + wv * 4 + kk) * 4 + mt) * 64 + ln) * 8);
      f32x4 acc[2][4];
#pragma unroll
      for (int nt = 0; nt < 2; nt++)
#pragma unroll
        for (int mt = 0; mt < 4; mt++) acc[nt][mt] = (f32x4){0.f, 0.f, 0.f, 0.f};
#pragma unroll
      for (int kk = 0; kk < 4; ++kk)
#pragma unroll
        for (int nt = 0; nt < 2; nt++)
#pragma unroll
          for (int mt = 0; mt < 4; mt++)
            acc[nt][mt] = __builtin_amdgcn_mfma_f32_16x16x32_bf16(a[kk][mt], Breg[kk][nt], acc[nt][mt], 0, 0, 0);
#pragma unroll
      for (int nt = 0; nt < 2; nt++)
#pragma unroll
        for (int mt = 0; mt < 4; mt++)
          *(f32x4*)(red + ((wv * 8 + nt * 4 + mt) * 64 + ln) * 4) = acc[nt][mt];
      __syncthreads();
#pragma unroll
      for (int it = 0; it < 8; ++it) {          // 2048 outputs, 8/thread
        int item = it * 256 + tid;
        int m = item >> 5, c = item & 31;
        int mt = m >> 4, lq = ((m & 15) >> 2) * 16, reg = m & 3;
        float s = bias_r[it];
        int base = ((c >> 4) * 4 + mt) * 64 + lq + (c & 15);
#pragma unroll
        for (int w = 0; w < 4; ++w) s += red[(w * 8 * 64 + base) * 4 + reg];
        dstage[((mt * 4 + (c >> 3)) * 16 + (m & 15)) * 8 + (c & 7)] = f2bf(fast_tanh(s));
      }
      __syncthreads();
      // d publish for the lazy y WG
      stc16(dbufR + (dw * 256 + tid) * 8, (const u64*)(dstage + tid * 8));
      // feat partial: A = d slice frags (from dstage), B = WcB, K=32
      short8 ad[4];
#pragma unroll
      for (int mt = 0; mt < 4; ++mt)
        ad[mt] = *(const short8*)(dstage + ((mt * 4 + (ln >> 4)) * 16 + (ln & 15)) * 8);
      f32x4 pacc[4][4];
#pragma unroll
      for (int nt = 0; nt < 4; ++nt)
#pragma unroll
        for (int mt = 0; mt < 4; ++mt) pacc[nt][mt] = (f32x4){0.f, 0.f, 0.f, 0.f};
#pragma unroll
      for (int nt = 0; nt < 4; ++nt)
#pragma unroll
        for (int mt = 0; mt < 4; ++mt)
          pacc[nt][mt] = __builtin_amdgcn_mfma_f32_16x16x32_bf16(ad[mt], WcB[nt], pacc[nt][mt], 0, 0, 0);
      {
        float* fs = featacc + (t & 3) * FACC_ELE;
#pragma unroll
        for (int nt = 0; nt < 4; ++nt) {
          int c = (wv * 4 + nt) * 16 + (ln & 15);
          int cb = (c >> 5) * 2048 + ((c & 31) >> 3) * 128 + (c & 7);
#pragma unroll
          for (int mt = 0; mt < 4; ++mt)
#pragma unroll
            for (int reg = 0; reg < 4; ++reg)
              atadd(fs + cb + mt * 512 + ((ln >> 4) * 4 + reg) * 8, pacc[nt][mt][reg]);
        }
      }
      VMCNT0();
      __syncthreads();
      if (tid == 0) {
        setflag(&dflag[dw * 16], (u32)(t + 1));
        (void)__hip_atomic_fetch_add(&fcnt[(t & 3) * 16], 1u,
                                     __ATOMIC_RELAXED, __HIP_MEMORY_SCOPE_AGENT);
      }
      r = rn; rn = (rn == 2) ? 0 : rn + 1;
    }
  } else {
    // ===== lazy y WG (off the recurrence): y = d @ W_out^T + b_out =====
    float* red = (float*)smem;                 // [4 wv][16 tile][64][4] = 64KB
    const int c15 = ln & 15, qq = ln >> 4;
    short8 WoR[2][4];
#pragma unroll
    for (int kk = 0; kk < 2; ++kk) {
      int koffo = (wv * 2 + kk) * 32 + qq * 8;
#pragma unroll
      for (int nt = 0; nt < 4; ++nt)
        WoR[kk][nt] = cvt8(W_out + (nt * 16 + c15) * 256 + koffo);
    }
    float bout_r = b_out[wv * 16 + c15];
    for (int t = 0; t < SEQ; ++t) {
      if (tid < 8) pollge(&dflag[tid * 16], (u32)(t + 1));
      __syncthreads();
      const u16* dbufR = dbase + (t & 1) * D_ELE;
      short8 da[2][4];
#pragma unroll
      for (int kk = 0; kk < 2; ++kk)
#pragma unroll
        for (int mt = 0; mt < 4; ++mt)
          da[kk][mt] = ldc16(dbufR + (((wv * 2 + kk) * 4 + mt) * 64 + ln) * 8);
      f32x4 acc[4][4];
#pragma unroll
      for (int nt = 0; nt < 4; nt++)
#pragma unroll
        for (int mt = 0; mt < 4; mt++) acc[nt][mt] = (f32x4){0.f, 0.f, 0.f, 0.f};
#pragma unroll
      for (int kk = 0; kk < 2; ++kk)
#pragma unroll
        for (int nt = 0; nt < 4; nt++)
#pragma unroll
          for (int mt = 0; mt < 4; mt++)
            acc[nt][mt] = __builtin_amdgcn_mfma_f32_16x16x32_bf16(da[kk][mt], WoR[kk][nt], acc[nt][mt], 0, 0, 0);
#pragma unroll
      for (int nt = 0; nt < 4; nt++)
#pragma unroll
        for (int mt = 0; mt < 4; mt++)
          *(f32x4*)(red + ((wv * 16 + nt * 4 + mt) * 64 + ln) * 4) = acc[nt][mt];
      __syncthreads();
#pragma unroll
      for (int mt = 0; mt < 4; ++mt) {
        f32x4 s = (f32x4){0.f, 0.f, 0.f, 0.f};
#pragma unroll
        for (int w2 = 0; w2 < 4; ++w2)
          s += *(const f32x4*)(red + ((w2 * 16 + wv * 4 + mt) * 64 + ln) * 4);
#pragma unroll
        for (int r2 = 0; r2 < 4; ++r2) {
          int row = mt * 16 + qq * 4 + r2;
          out[t * 4096 + row * 64 + wv * 16 + c15] = s[r2] + bout_r;
        }
      }
      __syncthreads();
    }
  }
}

extern "C" void kernel_launch(void* const* d_in, const int* in_sizes, int n_in,
                              void* d_out, int out_size, void* d_ws, size_t ws_size,
                              hipStream_t stream) {
  const float* x     = (const float*)d_in[0];
  const float* msel  = (const float*)d_in[1];
  const float* W_fx  = (const float*)d_in[2];
  const float* b_fx  = (const float*)d_in[3];
  const float* W_ih  = (const float*)d_in[4];
  const float* W_hh  = (const float*)d_in[5];
  const float* b_ih  = (const float*)d_in[6];
  const float* b_hh  = (const float*)d_in[7];
  const float* W_hx  = (const float*)d_in[8];
  const float* b_hx  = (const float*)d_in[9];
  const float* W_out = (const float*)d_in[10];
  const float* b_out = (const float*)d_in[11];

  uint8_t* ws = (uint8_t*)d_ws;
  u16*   Abase   = (u16*)ws;                  // ring of 3 x 98304 B
  u16*   dbase   = (u16*)(ws + 294912);       // ring of 2 x 32768 B
  u32*   flags   = (u32*)(ws + 360448);       // 6144 B (u32[1536])
  float* featacc = (float*)(ws + 368640);     // 4 x 65536 B
  float* bcomb   = (float*)(ws + 630784);     // 1024 B
  u16*   Wcpack  = (u16*)(ws + 631808);       // 131072 B
  u16*   ftf     = (u16*)(ws + 762880);       // 256 x 32768 B = 8 MB

  prep_misc<<<23, 256, 0, stream>>>(W_fx, b_fx, W_out, b_out,
                                    Abase, flags, featacc, bcomb, Wcpack);
  prep_ftf<<<256, 256, 0, stream>>>(x, W_fx, b_fx, ftf);
  rnn_kernel<<<NWG, 256, 0, stream>>>(x, msel, W_ih, W_hh, b_ih, b_hh,
                                      W_hx, b_hx, W_out, b_out,
                                      (float*)d_out, Abase, dbase, flags,
                                      featacc, bcomb, Wcpack, ftf);
}